// Round 1
// baseline (4170.652 us; speedup 1.0000x reference)
//
#include <hip/hip_runtime.h>

#define Bsz 256
#define Gn 100
#define GG 10000
#define IND 128
#define KD 32
#define NH 8
#define S_TOT 10000
#define CHUNK 2048               // Bsz*NH
#define NODE_ELEMS 10240000      // 4*Bsz*GG
#define POS_ELEMS  5120000       // 2*Bsz*GG
#define NORMC 0.17677669529663687f
#define LOG2E 1.4426950408889634f
#define TWO_LOG2E 2.8853900817779268f

// ws layout (bytes)
#define V_OFF    40960000ull
#define YS_OFF   67174400ull
#define WS_NEEDED 149094400ull

// out layout (floats)
#define OUT_H 3276800
#define OUT_C 3278848

__global__ void k_wsfail(float* out, float v) { out[0] = v; }

// ---------------- kernel 1: Q/K projection + node compatibility ----------------
// grid 1024 = h*256+b, 256 threads
__global__ __launch_bounds__(256) void k_qk_comp(const float* __restrict__ X,
        const float* __restrict__ Wq, const float* __restrict__ Wk,
        float* __restrict__ comp)
{
    int h = blockIdx.x >> 8, b = blockIdx.x & 255;
    __shared__ float Qs[Gn * 33];
    __shared__ float Ks[Gn * 33];
    const float* Xb = X + (size_t)b * Gn * IND;
    const float* wq = Wq + h * IND * KD;
    const float* wk = Wk + h * IND * KD;
    int k = threadIdx.x & 31, ii = threadIdx.x >> 5;
    for (int i0 = 0; i0 < Gn; i0 += 8) {
        int i = i0 + ii;
        if (i < Gn) {
            float aq = 0.f, ak = 0.f;
            const float* xr = Xb + i * IND;
            #pragma unroll 8
            for (int c = 0; c < IND; ++c) {
                float x = xr[c];
                aq = fmaf(x, wq[c * KD + k], aq);
                ak = fmaf(x, wk[c * KD + k], ak);
            }
            Qs[i * 33 + k] = aq;
            Ks[i * 33 + k] = ak;
        }
    }
    __syncthreads();
    float* cb = comp + (size_t)blockIdx.x * GG;
    for (int idx = threadIdx.x; idx < GG; idx += 256) {
        int i = idx / 100, j = idx - i * 100;
        float acc = 0.f;
        #pragma unroll
        for (int kk = 0; kk < KD; ++kk)
            acc = fmaf(Qs[i * 33 + kk], Ks[j * 33 + kk], acc);
        cb[idx] = acc * NORMC;
    }
}

// ---------------- kernel 2: V projection ----------------
// grid 2048 = h*256+b, 256 threads
__global__ __launch_bounds__(256) void k_vproj(const float* __restrict__ X,
        const float* __restrict__ Wv, float* __restrict__ V)
{
    int h = blockIdx.x >> 8, b = blockIdx.x & 255;
    __shared__ float Xs[Gn * IND];
    const float4* X4 = (const float4*)(X + (size_t)b * Gn * IND);
    float4* Xs4 = (float4*)Xs;
    for (int i = threadIdx.x; i < Gn * IND / 4; i += 256) Xs4[i] = X4[i];
    __syncthreads();
    const float* wv = Wv + h * IND * KD;
    int k = threadIdx.x & 31, ii = threadIdx.x >> 5;
    float* vb = V + (size_t)blockIdx.x * (Gn * KD);
    for (int i0 = 0; i0 < Gn; i0 += 8) {
        int i = i0 + ii;
        if (i < Gn) {
            float a = 0.f;
            #pragma unroll 8
            for (int c = 0; c < IND; ++c)
                a = fmaf(Xs[i * IND + c], wv[c * KD + k], a);
            vb[i * KD + k] = a;
        }
    }
}

// ---------------- kernel 3: LSTM over 10000 steps ----------------
// 32 blocks x 64 threads; 8 lanes per batch (lane = unit), 8 batches per wave
__global__ __launch_bounds__(64) void k_lstm(
        const float* __restrict__ comp_ws, const float* __restrict__ pos,
        const float* __restrict__ best, const float* __restrict__ cost,
        const float* __restrict__ bcost, const float* __restrict__ h0,
        const float* __restrict__ c0, const float* __restrict__ Wih,
        const float* __restrict__ Whh, const float* __restrict__ bih,
        const float* __restrict__ bhh, float* __restrict__ ys,
        float* __restrict__ outhc)
{
    int lane = threadIdx.x;
    int u = lane & 7, bl = lane >> 3;
    int b = blockIdx.x * 8 + bl;
    int b8 = b * 8;

    float wih[4][8], whh[4][8], cb[4];
    #pragma unroll
    for (int q = 0; q < 4; ++q) {
        int r = q * 8 + u;
        float ks = (q == 2) ? TWO_LOG2E : LOG2E;   // fold log2e (2*log2e for tanh gate)
        #pragma unroll
        for (int v = 0; v < 8; ++v) wih[q][v] = Wih[r * 10 + v] * ks;
        #pragma unroll
        for (int v = 0; v < 8; ++v) whh[q][v] = Whh[r * 8 + v] * ks;
        cb[q] = (bih[r] + bhh[r] + Wih[r * 10 + 8] * cost[b] + Wih[r * 10 + 9] * bcost[b]) * ks;
    }
    float hcur = h0[b8 + u], ccur = c0[b8 + u];

    float4 xa0, xa1, xb0, xb1;
    auto ldx = [&](int s, float4& lo, float4& hi) {
        int off = s * CHUNK + b8;
        const float* p;
        if (s < 5000)      p = comp_ws + off;
        else if (s < 7500) p = pos + (off - NODE_ELEMS);
        else               p = best + (off - NODE_ELEMS - POS_ELEMS);
        const float4* p4 = (const float4*)p;
        lo = p4[0]; hi = p4[1];
    };
    ldx(0, xa0, xa1);
    ldx(1, xb0, xb1);

    for (int s = 0; s < S_TOT; ++s) {
        float xr[8] = {xa0.x, xa0.y, xa0.z, xa0.w, xa1.x, xa1.y, xa1.z, xa1.w};
        xa0 = xb0; xa1 = xb1;
        int nxt = (s + 2 < S_TOT) ? s + 2 : S_TOT - 1;
        ldx(nxt, xb0, xb1);

        float g0 = cb[0], g1 = cb[1], g2 = cb[2], g3 = cb[3];
        #pragma unroll
        for (int v = 0; v < 8; ++v) {
            g0 = fmaf(wih[0][v], xr[v], g0);
            g1 = fmaf(wih[1][v], xr[v], g1);
            g2 = fmaf(wih[2][v], xr[v], g2);
            g3 = fmaf(wih[3][v], xr[v], g3);
        }

        // all-gather the 8 h values of this batch (lanes base..base+7), 1 LDS-pipe trip
        int hb = __float_as_int(hcur);
        float hv[8];
        hv[0] = __int_as_float(__builtin_amdgcn_ds_swizzle(hb, 0x18 | (0 << 5)));
        hv[1] = __int_as_float(__builtin_amdgcn_ds_swizzle(hb, 0x18 | (1 << 5)));
        hv[2] = __int_as_float(__builtin_amdgcn_ds_swizzle(hb, 0x18 | (2 << 5)));
        hv[3] = __int_as_float(__builtin_amdgcn_ds_swizzle(hb, 0x18 | (3 << 5)));
        hv[4] = __int_as_float(__builtin_amdgcn_ds_swizzle(hb, 0x18 | (4 << 5)));
        hv[5] = __int_as_float(__builtin_amdgcn_ds_swizzle(hb, 0x18 | (5 << 5)));
        hv[6] = __int_as_float(__builtin_amdgcn_ds_swizzle(hb, 0x18 | (6 << 5)));
        hv[7] = __int_as_float(__builtin_amdgcn_ds_swizzle(hb, 0x18 | (7 << 5)));
        #pragma unroll
        for (int v = 0; v < 8; ++v) {
            g0 = fmaf(whh[0][v], hv[v], g0);
            g1 = fmaf(whh[1][v], hv[v], g1);
            g2 = fmaf(whh[2][v], hv[v], g2);
            g3 = fmaf(whh[3][v], hv[v], g3);
        }

        // activations: gates pre-scaled so sigma(z)=rcp(1+exp2(-g)); tanh(z)=2*rcp(1+exp2(-g))-1
        float si = __builtin_amdgcn_rcpf(1.f + __builtin_amdgcn_exp2f(-g0));
        float sf = __builtin_amdgcn_rcpf(1.f + __builtin_amdgcn_exp2f(-g1));
        float tg = fmaf(2.f, __builtin_amdgcn_rcpf(1.f + __builtin_amdgcn_exp2f(-g2)), -1.f);
        float so = __builtin_amdgcn_rcpf(1.f + __builtin_amdgcn_exp2f(-g3));
        ccur = fmaf(sf, ccur, si * tg);
        float tc = fmaf(2.f, __builtin_amdgcn_rcpf(1.f + __builtin_amdgcn_exp2f(ccur * -TWO_LOG2E)), -1.f);
        hcur = so * tc;

        ys[s * CHUNK + b8 + u] = hcur;
    }
    outhc[OUT_H + b8 + u] = hcur;
    outhc[OUT_C + b8 + u] = ccur;
}

// ---------------- kernel 4: softmax rows + attn @ V ----------------
// grid 2048 = h*256+b, 256 threads
__global__ __launch_bounds__(256) void k_softmax_av(const float* __restrict__ ys,
        const float* __restrict__ V, float* __restrict__ heads)
{
    __shared__ float P[Gn * 101];
    __shared__ float Vs[Gn * 33];
    const float* ysrc = ys + (size_t)blockIdx.x * GG;
    for (int idx = threadIdx.x; idx < GG; idx += 256) {
        int i = idx / 100, j = idx - i * 100;
        P[i * 101 + j] = ysrc[idx];
    }
    const float* vsrc = V + (size_t)blockIdx.x * (Gn * KD);
    for (int idx = threadIdx.x; idx < Gn * KD; idx += 256) {
        int i = idx >> 5, d = idx & 31;
        Vs[i * 33 + d] = vsrc[idx];
    }
    __syncthreads();
    if (threadIdx.x < Gn) {
        float* row = P + threadIdx.x * 101;
        float m = -1e30f;
        for (int j = 0; j < Gn; ++j) m = fmaxf(m, row[j]);
        float ss = 0.f;
        for (int j = 0; j < Gn; ++j) {
            float e = __builtin_amdgcn_exp2f((row[j] - m) * LOG2E);
            row[j] = e; ss += e;
        }
        float r = __builtin_amdgcn_rcpf(ss);
        for (int j = 0; j < Gn; ++j) row[j] *= r;
    }
    __syncthreads();
    int d = threadIdx.x & 31, ii = threadIdx.x >> 5;
    float* hb = heads + (size_t)blockIdx.x * (Gn * KD);
    for (int i0 = 0; i0 < Gn; i0 += 8) {
        int i = i0 + ii;
        if (i < Gn) {
            float acc = 0.f;
            #pragma unroll 4
            for (int j = 0; j < Gn; ++j)
                acc = fmaf(P[i * 101 + j], Vs[j * 33 + d], acc);
            hb[i * KD + d] = acc;
        }
    }
}

// ---------------- kernel 5: output projection ----------------
// grid 256 (= b), 256 threads; out[b,i,e] = sum_{h,d} heads[h,b,i,d]*Wo[h,d,e]
__global__ __launch_bounds__(256) void k_outproj(const float* __restrict__ heads,
        const float* __restrict__ Wo, float* __restrict__ out)
{
    int b = blockIdx.x;
    int e = threadIdx.x & 127, half = threadIdx.x >> 7;
    for (int p = 0; p < 13; ++p) {
        int r0 = p * 8 + half * 4;
        float acc0 = 0.f, acc1 = 0.f, acc2 = 0.f, acc3 = 0.f;
        for (int h = 0; h < NH; ++h) {
            const float* hs = heads + (size_t)h * (256 * Gn * KD) + (size_t)b * (Gn * KD);
            const float* wsrc = Wo + h * (KD * IND);
            #pragma unroll 8
            for (int d = 0; d < KD; ++d) {
                float w = wsrc[d * IND + e];
                if (r0 + 3 < Gn) {
                    acc0 = fmaf(hs[(r0 + 0) * KD + d], w, acc0);
                    acc1 = fmaf(hs[(r0 + 1) * KD + d], w, acc1);
                    acc2 = fmaf(hs[(r0 + 2) * KD + d], w, acc2);
                    acc3 = fmaf(hs[(r0 + 3) * KD + d], w, acc3);
                } else {
                    if (r0 + 0 < Gn) acc0 = fmaf(hs[(r0 + 0) * KD + d], w, acc0);
                    if (r0 + 1 < Gn) acc1 = fmaf(hs[(r0 + 1) * KD + d], w, acc1);
                    if (r0 + 2 < Gn) acc2 = fmaf(hs[(r0 + 2) * KD + d], w, acc2);
                    if (r0 + 3 < Gn) acc3 = fmaf(hs[(r0 + 3) * KD + d], w, acc3);
                }
            }
        }
        if (r0 + 0 < Gn) out[((size_t)b * Gn + r0 + 0) * IND + e] = acc0;
        if (r0 + 1 < Gn) out[((size_t)b * Gn + r0 + 1) * IND + e] = acc1;
        if (r0 + 2 < Gn) out[((size_t)b * Gn + r0 + 2) * IND + e] = acc2;
        if (r0 + 3 < Gn) out[((size_t)b * Gn + r0 + 3) * IND + e] = acc3;
    }
}

extern "C" void kernel_launch(void* const* d_in, const int* in_sizes, int n_in,
                              void* d_out, int out_size, void* d_ws, size_t ws_size,
                              hipStream_t stream) {
    const float* X     = (const float*)d_in[0];
    const float* pos   = (const float*)d_in[1];
    const float* best  = (const float*)d_in[2];
    const float* cost  = (const float*)d_in[3];
    const float* bcost = (const float*)d_in[4];
    const float* h0    = (const float*)d_in[5];
    const float* c0    = (const float*)d_in[6];
    const float* Wq    = (const float*)d_in[7];
    const float* Wk    = (const float*)d_in[8];
    const float* Wv    = (const float*)d_in[9];
    const float* Wo    = (const float*)d_in[10];
    const float* Wih   = (const float*)d_in[11];
    const float* Whh   = (const float*)d_in[12];
    const float* bih   = (const float*)d_in[13];
    const float* bhh   = (const float*)d_in[14];
    float* out = (float*)d_out;
    char* ws = (char*)d_ws;

    if (ws_size < WS_NEEDED) {
        // report actual ws_size through the absmax printout for debugging
        k_wsfail<<<1, 1, 0, stream>>>(out, (float)ws_size);
        return;
    }

    float* comp   = (float*)(ws);
    float* Vw     = (float*)(ws + V_OFF);
    float* ysw    = (float*)(ws + YS_OFF);
    float* headsw = (float*)(ws);  // reuse comp region (consumed before kernel 4)

    k_qk_comp<<<1024, 256, 0, stream>>>(X, Wq, Wk, comp);
    k_vproj<<<2048, 256, 0, stream>>>(X, Wv, Vw);
    k_lstm<<<32, 64, 0, stream>>>(comp, pos, best, cost, bcost, h0, c0,
                                  Wih, Whh, bih, bhh, ysw, out);
    k_softmax_av<<<2048, 256, 0, stream>>>(ysw, Vw, headsw);
    k_outproj<<<256, 256, 0, stream>>>(headsw, Wo, out);
}

// Round 2
// 3069.266 us; speedup vs baseline: 1.3588x; 1.3588x over previous
//
#include <hip/hip_runtime.h>

#define Bsz 256
#define Gn 100
#define GG 10000
#define IND 128
#define KD 32
#define NH 8
#define S_TOT 10000
#define CHUNK 2048               // Bsz*NH
#define NODE_ELEMS 10240000      // 4*Bsz*GG
#define POS_ELEMS  5120000       // 2*Bsz*GG
#define NORMC 0.17677669529663687f
#define LOG2E 1.4426950408889634f
#define TWO_LOG2E 2.8853900817779268f

// ws layout (bytes)
#define V_OFF    40960000ull
#define YS_OFF   67174400ull
#define WS_NEEDED 149094400ull

// out layout (floats)
#define OUT_H 3276800
#define OUT_C 3278848

__global__ void k_wsfail(float* out, float v) { out[0] = v; }

// ---------------- kernel 1: Q/K projection + node compatibility ----------------
__global__ __launch_bounds__(256) void k_qk_comp(const float* __restrict__ X,
        const float* __restrict__ Wq, const float* __restrict__ Wk,
        float* __restrict__ comp)
{
    int h = blockIdx.x >> 8, b = blockIdx.x & 255;
    __shared__ float Qs[Gn * 33];
    __shared__ float Ks[Gn * 33];
    const float* Xb = X + (size_t)b * Gn * IND;
    const float* wq = Wq + h * IND * KD;
    const float* wk = Wk + h * IND * KD;
    int k = threadIdx.x & 31, ii = threadIdx.x >> 5;
    for (int i0 = 0; i0 < Gn; i0 += 8) {
        int i = i0 + ii;
        if (i < Gn) {
            float aq = 0.f, ak = 0.f;
            const float* xr = Xb + i * IND;
            #pragma unroll 8
            for (int c = 0; c < IND; ++c) {
                float x = xr[c];
                aq = fmaf(x, wq[c * KD + k], aq);
                ak = fmaf(x, wk[c * KD + k], ak);
            }
            Qs[i * 33 + k] = aq;
            Ks[i * 33 + k] = ak;
        }
    }
    __syncthreads();
    float* cb = comp + (size_t)blockIdx.x * GG;
    for (int idx = threadIdx.x; idx < GG; idx += 256) {
        int i = idx / 100, j = idx - i * 100;
        float acc = 0.f;
        #pragma unroll
        for (int kk = 0; kk < KD; ++kk)
            acc = fmaf(Qs[i * 33 + kk], Ks[j * 33 + kk], acc);
        cb[idx] = acc * NORMC;
    }
}

// ---------------- kernel 2: V projection ----------------
__global__ __launch_bounds__(256) void k_vproj(const float* __restrict__ X,
        const float* __restrict__ Wv, float* __restrict__ V)
{
    int h = blockIdx.x >> 8, b = blockIdx.x & 255;
    __shared__ float Xs[Gn * IND];
    const float4* X4 = (const float4*)(X + (size_t)b * Gn * IND);
    float4* Xs4 = (float4*)Xs;
    for (int i = threadIdx.x; i < Gn * IND / 4; i += 256) Xs4[i] = X4[i];
    __syncthreads();
    const float* wv = Wv + h * IND * KD;
    int k = threadIdx.x & 31, ii = threadIdx.x >> 5;
    float* vb = V + (size_t)blockIdx.x * (Gn * KD);
    for (int i0 = 0; i0 < Gn; i0 += 8) {
        int i = i0 + ii;
        if (i < Gn) {
            float a = 0.f;
            #pragma unroll 8
            for (int c = 0; c < IND; ++c)
                a = fmaf(Xs[i * IND + c], wv[c * KD + k], a);
            vb[i * KD + k] = a;
        }
    }
}

// ---------------- kernel 3: LSTM over 10000 steps ----------------
// 32 blocks x 64 threads; lane = (batch-in-wave)*8 + unit.
// h all-gather via DPP XOR butterfly (masks 1,2,7) — no LDS, no lgkmcnt.
// x prefetch: 4-deep static slots, segment loops (no per-step pointer select).

#define DPP_GATHER() \
    int hbi = __float_as_int(hcur); \
    int d1 = __builtin_amdgcn_update_dpp(0, hbi, 0xB1, 0xF, 0xF, true); \
    int d2 = __builtin_amdgcn_update_dpp(0, hbi, 0x4E, 0xF, 0xF, true); \
    int d3 = __builtin_amdgcn_update_dpp(0, d1,  0x4E, 0xF, 0xF, true); \
    int d7 = __builtin_amdgcn_update_dpp(0, hbi, 0x141, 0xF, 0xF, true); \
    int d6 = __builtin_amdgcn_update_dpp(0, d1,  0x141, 0xF, 0xF, true); \
    int d5 = __builtin_amdgcn_update_dpp(0, d2,  0x141, 0xF, 0xF, true); \
    int d4 = __builtin_amdgcn_update_dpp(0, d3,  0x141, 0xF, 0xF, true); \
    float hv0 = hcur; \
    float hv1 = __int_as_float(d1); \
    float hv2 = __int_as_float(d2); \
    float hv3 = __int_as_float(d3); \
    float hv4 = __int_as_float(d7); \
    float hv5 = __int_as_float(d6); \
    float hv6 = __int_as_float(d5); \
    float hv7 = __int_as_float(d4);

#define LSTM_BODY(LO, HI, TT, SEGN, SB, YP) do { \
    float g0 = cbv[0], g1 = cbv[1], g2 = cbv[2], g3 = cbv[3]; \
    float x0=LO.x, x1=LO.y, x2=LO.z, x3=LO.w, x4=HI.x, x5=HI.y, x6=HI.z, x7=HI.w; \
    g0=fmaf(wi[0][0],x0,g0); g1=fmaf(wi[1][0],x0,g1); g2=fmaf(wi[2][0],x0,g2); g3=fmaf(wi[3][0],x0,g3); \
    g0=fmaf(wi[0][1],x1,g0); g1=fmaf(wi[1][1],x1,g1); g2=fmaf(wi[2][1],x1,g2); g3=fmaf(wi[3][1],x1,g3); \
    g0=fmaf(wi[0][2],x2,g0); g1=fmaf(wi[1][2],x2,g1); g2=fmaf(wi[2][2],x2,g2); g3=fmaf(wi[3][2],x2,g3); \
    g0=fmaf(wi[0][3],x3,g0); g1=fmaf(wi[1][3],x3,g1); g2=fmaf(wi[2][3],x3,g2); g3=fmaf(wi[3][3],x3,g3); \
    g0=fmaf(wi[0][4],x4,g0); g1=fmaf(wi[1][4],x4,g1); g2=fmaf(wi[2][4],x4,g2); g3=fmaf(wi[3][4],x4,g3); \
    g0=fmaf(wi[0][5],x5,g0); g1=fmaf(wi[1][5],x5,g1); g2=fmaf(wi[2][5],x5,g2); g3=fmaf(wi[3][5],x5,g3); \
    g0=fmaf(wi[0][6],x6,g0); g1=fmaf(wi[1][6],x6,g1); g2=fmaf(wi[2][6],x6,g2); g3=fmaf(wi[3][6],x6,g3); \
    g0=fmaf(wi[0][7],x7,g0); g1=fmaf(wi[1][7],x7,g1); g2=fmaf(wi[2][7],x7,g2); g3=fmaf(wi[3][7],x7,g3); \
    { int pf = (TT)+4; pf = (pf < (SEGN)) ? pf : ((SEGN)-1); \
      const float4* pp = (const float4*)((SB) + (size_t)pf*CHUNK); \
      LO = pp[0]; HI = pp[1]; } \
    DPP_GATHER(); \
    g0=fmaf(wh[0][0],hv0,g0); g1=fmaf(wh[1][0],hv0,g1); g2=fmaf(wh[2][0],hv0,g2); g3=fmaf(wh[3][0],hv0,g3); \
    g0=fmaf(wh[0][1],hv1,g0); g1=fmaf(wh[1][1],hv1,g1); g2=fmaf(wh[2][1],hv1,g2); g3=fmaf(wh[3][1],hv1,g3); \
    g0=fmaf(wh[0][2],hv2,g0); g1=fmaf(wh[1][2],hv2,g1); g2=fmaf(wh[2][2],hv2,g2); g3=fmaf(wh[3][2],hv2,g3); \
    g0=fmaf(wh[0][3],hv3,g0); g1=fmaf(wh[1][3],hv3,g1); g2=fmaf(wh[2][3],hv3,g2); g3=fmaf(wh[3][3],hv3,g3); \
    g0=fmaf(wh[0][4],hv4,g0); g1=fmaf(wh[1][4],hv4,g1); g2=fmaf(wh[2][4],hv4,g2); g3=fmaf(wh[3][4],hv4,g3); \
    g0=fmaf(wh[0][5],hv5,g0); g1=fmaf(wh[1][5],hv5,g1); g2=fmaf(wh[2][5],hv5,g2); g3=fmaf(wh[3][5],hv5,g3); \
    g0=fmaf(wh[0][6],hv6,g0); g1=fmaf(wh[1][6],hv6,g1); g2=fmaf(wh[2][6],hv6,g2); g3=fmaf(wh[3][6],hv6,g3); \
    g0=fmaf(wh[0][7],hv7,g0); g1=fmaf(wh[1][7],hv7,g1); g2=fmaf(wh[2][7],hv7,g2); g3=fmaf(wh[3][7],hv7,g3); \
    float si = __builtin_amdgcn_rcpf(1.f + __builtin_amdgcn_exp2f(-g0)); \
    float sf = __builtin_amdgcn_rcpf(1.f + __builtin_amdgcn_exp2f(-g1)); \
    float tg = fmaf(2.f, __builtin_amdgcn_rcpf(1.f + __builtin_amdgcn_exp2f(-g2)), -1.f); \
    float so = __builtin_amdgcn_rcpf(1.f + __builtin_amdgcn_exp2f(-g3)); \
    ccur = fmaf(sf, ccur, si * tg); \
    float tc = fmaf(2.f, __builtin_amdgcn_rcpf(1.f + __builtin_amdgcn_exp2f(ccur * -TWO_LOG2E)), -1.f); \
    hcur = so * tc; \
    (YP)[(size_t)(TT)*CHUNK] = hcur; \
} while (0)

__global__ __launch_bounds__(64) void k_lstm(
        const float* __restrict__ comp_ws, const float* __restrict__ pos,
        const float* __restrict__ best, const float* __restrict__ cost,
        const float* __restrict__ bcost, const float* __restrict__ h0,
        const float* __restrict__ c0, const float* __restrict__ Wih,
        const float* __restrict__ Whh, const float* __restrict__ bih,
        const float* __restrict__ bhh, float* __restrict__ ys,
        float* __restrict__ outhc)
{
    int lane = threadIdx.x;
    int u = lane & 7, bl = lane >> 3;
    int b = blockIdx.x * 8 + bl;
    int b8 = b * 8;

    // per-lane weights; Whh in XOR-gather order u^{0,1,2,3,7,6,5,4}
    const int xm[8] = {0, 1, 2, 3, 7, 6, 5, 4};
    float wi[4][8], wh[4][8], cbv[4];
    #pragma unroll
    for (int q = 0; q < 4; ++q) {
        int r = q * 8 + u;
        float ks = (q == 2) ? TWO_LOG2E : LOG2E;
        #pragma unroll
        for (int v = 0; v < 8; ++v) wi[q][v] = Wih[r * 10 + v] * ks;
        #pragma unroll
        for (int j = 0; j < 8; ++j) wh[q][j] = Whh[r * 8 + (u ^ xm[j])] * ks;
        cbv[q] = (bih[r] + bhh[r] + Wih[r * 10 + 8] * cost[b] + Wih[r * 10 + 9] * bcost[b]) * ks;
    }
    float hcur = h0[b8 + u], ccur = c0[b8 + u];

    #define RUN_SEG(BASE, YSOFF, SEGN) do { \
        const float* sb = (BASE) + b8; \
        float* yp = ys + (size_t)(YSOFF)*CHUNK + b8 + u; \
        float4 L0,H0,L1,H1,L2,H2,L3,H3; \
        { const float4* p=(const float4*)(sb + 0*CHUNK); L0=p[0]; H0=p[1]; } \
        { const float4* p=(const float4*)(sb + 1*CHUNK); L1=p[0]; H1=p[1]; } \
        { const float4* p=(const float4*)(sb + 2*CHUNK); L2=p[0]; H2=p[1]; } \
        { const float4* p=(const float4*)(sb + 3*CHUNK); L3=p[0]; H3=p[1]; } \
        for (int t = 0; t < (SEGN); t += 4) { \
            LSTM_BODY(L0, H0, t+0, SEGN, sb, yp); \
            LSTM_BODY(L1, H1, t+1, SEGN, sb, yp); \
            LSTM_BODY(L2, H2, t+2, SEGN, sb, yp); \
            LSTM_BODY(L3, H3, t+3, SEGN, sb, yp); \
        } \
    } while (0)

    RUN_SEG(comp_ws, 0,    5000);
    RUN_SEG(pos,     5000, 2500);
    RUN_SEG(best,    7500, 2500);

    outhc[OUT_H + b8 + u] = hcur;
    outhc[OUT_C + b8 + u] = ccur;
}

// ---------------- kernel 4: softmax rows + attn @ V ----------------
__global__ __launch_bounds__(256) void k_softmax_av(const float* __restrict__ ys,
        const float* __restrict__ V, float* __restrict__ heads)
{
    __shared__ float P[Gn * 101];
    __shared__ float Vs[Gn * 33];
    const float* ysrc = ys + (size_t)blockIdx.x * GG;
    for (int idx = threadIdx.x; idx < GG; idx += 256) {
        int i = idx / 100, j = idx - i * 100;
        P[i * 101 + j] = ysrc[idx];
    }
    const float* vsrc = V + (size_t)blockIdx.x * (Gn * KD);
    for (int idx = threadIdx.x; idx < Gn * KD; idx += 256) {
        int i = idx >> 5, d = idx & 31;
        Vs[i * 33 + d] = vsrc[idx];
    }
    __syncthreads();
    if (threadIdx.x < Gn) {
        float* row = P + threadIdx.x * 101;
        float m = -1e30f;
        for (int j = 0; j < Gn; ++j) m = fmaxf(m, row[j]);
        float ss = 0.f;
        for (int j = 0; j < Gn; ++j) {
            float e = __builtin_amdgcn_exp2f((row[j] - m) * LOG2E);
            row[j] = e; ss += e;
        }
        float r = __builtin_amdgcn_rcpf(ss);
        for (int j = 0; j < Gn; ++j) row[j] *= r;
    }
    __syncthreads();
    int d = threadIdx.x & 31, ii = threadIdx.x >> 5;
    float* hb = heads + (size_t)blockIdx.x * (Gn * KD);
    for (int i0 = 0; i0 < Gn; i0 += 8) {
        int i = i0 + ii;
        if (i < Gn) {
            float acc = 0.f;
            #pragma unroll 4
            for (int j = 0; j < Gn; ++j)
                acc = fmaf(P[i * 101 + j], Vs[j * 33 + d], acc);
            hb[i * KD + d] = acc;
        }
    }
}

// ---------------- kernel 5: output projection ----------------
__global__ __launch_bounds__(256) void k_outproj(const float* __restrict__ heads,
        const float* __restrict__ Wo, float* __restrict__ out)
{
    int b = blockIdx.x;
    int e = threadIdx.x & 127, half = threadIdx.x >> 7;
    for (int p = 0; p < 13; ++p) {
        int r0 = p * 8 + half * 4;
        float acc0 = 0.f, acc1 = 0.f, acc2 = 0.f, acc3 = 0.f;
        for (int h = 0; h < NH; ++h) {
            const float* hs = heads + (size_t)h * (256 * Gn * KD) + (size_t)b * (Gn * KD);
            const float* wsrc = Wo + h * (KD * IND);
            #pragma unroll 8
            for (int d = 0; d < KD; ++d) {
                float w = wsrc[d * IND + e];
                if (r0 + 3 < Gn) {
                    acc0 = fmaf(hs[(r0 + 0) * KD + d], w, acc0);
                    acc1 = fmaf(hs[(r0 + 1) * KD + d], w, acc1);
                    acc2 = fmaf(hs[(r0 + 2) * KD + d], w, acc2);
                    acc3 = fmaf(hs[(r0 + 3) * KD + d], w, acc3);
                } else {
                    if (r0 + 0 < Gn) acc0 = fmaf(hs[(r0 + 0) * KD + d], w, acc0);
                    if (r0 + 1 < Gn) acc1 = fmaf(hs[(r0 + 1) * KD + d], w, acc1);
                    if (r0 + 2 < Gn) acc2 = fmaf(hs[(r0 + 2) * KD + d], w, acc2);
                    if (r0 + 3 < Gn) acc3 = fmaf(hs[(r0 + 3) * KD + d], w, acc3);
                }
            }
        }
        if (r0 + 0 < Gn) out[((size_t)b * Gn + r0 + 0) * IND + e] = acc0;
        if (r0 + 1 < Gn) out[((size_t)b * Gn + r0 + 1) * IND + e] = acc1;
        if (r0 + 2 < Gn) out[((size_t)b * Gn + r0 + 2) * IND + e] = acc2;
        if (r0 + 3 < Gn) out[((size_t)b * Gn + r0 + 3) * IND + e] = acc3;
    }
}

extern "C" void kernel_launch(void* const* d_in, const int* in_sizes, int n_in,
                              void* d_out, int out_size, void* d_ws, size_t ws_size,
                              hipStream_t stream) {
    const float* X     = (const float*)d_in[0];
    const float* pos   = (const float*)d_in[1];
    const float* best  = (const float*)d_in[2];
    const float* cost  = (const float*)d_in[3];
    const float* bcost = (const float*)d_in[4];
    const float* h0    = (const float*)d_in[5];
    const float* c0    = (const float*)d_in[6];
    const float* Wq    = (const float*)d_in[7];
    const float* Wk    = (const float*)d_in[8];
    const float* Wv    = (const float*)d_in[9];
    const float* Wo    = (const float*)d_in[10];
    const float* Wih   = (const float*)d_in[11];
    const float* Whh   = (const float*)d_in[12];
    const float* bih   = (const float*)d_in[13];
    const float* bhh   = (const float*)d_in[14];
    float* out = (float*)d_out;
    char* ws = (char*)d_ws;

    if (ws_size < WS_NEEDED) {
        k_wsfail<<<1, 1, 0, stream>>>(out, (float)ws_size);
        return;
    }

    float* comp   = (float*)(ws);
    float* Vw     = (float*)(ws + V_OFF);
    float* ysw    = (float*)(ws + YS_OFF);
    float* headsw = (float*)(ws);  // reuse comp region (consumed before kernel 4)

    k_qk_comp<<<1024, 256, 0, stream>>>(X, Wq, Wk, comp);
    k_vproj<<<2048, 256, 0, stream>>>(X, Wv, Vw);
    k_lstm<<<32, 64, 0, stream>>>(comp, pos, best, cost, bcost, h0, c0,
                                  Wih, Whh, bih, bhh, ysw, out);
    k_softmax_av<<<2048, 256, 0, stream>>>(ysw, Vw, headsw);
    k_outproj<<<256, 256, 0, stream>>>(headsw, Wo, out);
}

// Round 3
// 2775.958 us; speedup vs baseline: 1.5024x; 1.1057x over previous
//
#include <hip/hip_runtime.h>

#define Bsz 256
#define Gn 100
#define GG 10000
#define IND 128
#define KD 32
#define NH 8
#define S_TOT 10000
#define CHUNK 2048               // Bsz*NH
#define GXROW 8192               // Bsz*32 floats per step
#define NODE_ELEMS 10240000      // 4*Bsz*GG
#define POS_ELEMS  5120000       // 2*Bsz*GG
#define N_ROWS 2560000           // S_TOT*Bsz
#define NORMC 0.17677669529663687f
#define LOG2E 1.4426950408889634f
#define TWO_LOG2E 2.8853900817779268f

// ws layout (bytes)
#define V_OFF    40960000ull
#define YS_OFF   67174400ull
#define GX_OFF   149094400ull
#define WS_FB    149094400ull                         // fallback minimum
#define WS_FAST  (GX_OFF + 327680000ull + 262144ull)  // + gx + 8-step pad

// out layout (floats)
#define OUT_H 3276800
#define OUT_C 3278848

__global__ void k_wsfail(float* out, float v) { out[0] = v; }

// ---------------- kernel 1: Q/K projection + node compatibility ----------------
__global__ __launch_bounds__(256) void k_qk_comp(const float* __restrict__ X,
        const float* __restrict__ Wq, const float* __restrict__ Wk,
        float* __restrict__ comp)
{
    int h = blockIdx.x >> 8, b = blockIdx.x & 255;
    __shared__ float Qs[Gn * 33];
    __shared__ float Ks[Gn * 33];
    const float* Xb = X + (size_t)b * Gn * IND;
    const float* wq = Wq + h * IND * KD;
    const float* wk = Wk + h * IND * KD;
    int k = threadIdx.x & 31, ii = threadIdx.x >> 5;
    for (int i0 = 0; i0 < Gn; i0 += 8) {
        int i = i0 + ii;
        if (i < Gn) {
            float aq = 0.f, ak = 0.f;
            const float* xr = Xb + i * IND;
            #pragma unroll 8
            for (int c = 0; c < IND; ++c) {
                float x = xr[c];
                aq = fmaf(x, wq[c * KD + k], aq);
                ak = fmaf(x, wk[c * KD + k], ak);
            }
            Qs[i * 33 + k] = aq;
            Ks[i * 33 + k] = ak;
        }
    }
    __syncthreads();
    float* cb = comp + (size_t)blockIdx.x * GG;
    for (int idx = threadIdx.x; idx < GG; idx += 256) {
        int i = idx / 100, j = idx - i * 100;
        float acc = 0.f;
        #pragma unroll
        for (int kk = 0; kk < KD; ++kk)
            acc = fmaf(Qs[i * 33 + kk], Ks[j * 33 + kk], acc);
        cb[idx] = acc * NORMC;
    }
}

// ---------------- kernel 2: V projection ----------------
__global__ __launch_bounds__(256) void k_vproj(const float* __restrict__ X,
        const float* __restrict__ Wv, float* __restrict__ V)
{
    int h = blockIdx.x >> 8, b = blockIdx.x & 255;
    __shared__ float Xs[Gn * IND];
    const float4* X4 = (const float4*)(X + (size_t)b * Gn * IND);
    float4* Xs4 = (float4*)Xs;
    for (int i = threadIdx.x; i < Gn * IND / 4; i += 256) Xs4[i] = X4[i];
    __syncthreads();
    const float* wv = Wv + h * IND * KD;
    int k = threadIdx.x & 31, ii = threadIdx.x >> 5;
    float* vb = V + (size_t)blockIdx.x * (Gn * KD);
    for (int i0 = 0; i0 < Gn; i0 += 8) {
        int i = i0 + ii;
        if (i < Gn) {
            float a = 0.f;
            #pragma unroll 8
            for (int c = 0; c < IND; ++c)
                a = fmaf(Xs[i * IND + c], wv[c * KD + k], a);
            vb[i * KD + k] = a;
        }
    }
}

// ---------------- kernel 2b: precompute x-half of LSTM gates ----------------
// gx[s][b][u][q] = ks_q * (bih+bhh + W_cost*cost[b] + W_bcost*bcost[b] + sum_v Wih*x[s,b,v])
// grid 2048 x 256; thread = (local row lr = t>>3, unit u = t&7); 32 rows per block-iter
__global__ __launch_bounds__(256) void k_gx(const float* __restrict__ comp,
        const float* __restrict__ pos, const float* __restrict__ best,
        const float* __restrict__ cost, const float* __restrict__ bcost,
        const float* __restrict__ Wih, const float* __restrict__ bih,
        const float* __restrict__ bhh, float* __restrict__ gx)
{
    int u = threadIdx.x & 7, lr = threadIdx.x >> 3;
    float wiu[4][8], wc[4], wbc[4], bs[4];
    #pragma unroll
    for (int q = 0; q < 4; ++q) {
        int r = q * 8 + u;
        float ks = (q == 2) ? TWO_LOG2E : LOG2E;
        #pragma unroll
        for (int v = 0; v < 8; ++v) wiu[q][v] = Wih[r * 10 + v] * ks;
        wc[q]  = Wih[r * 10 + 8] * ks;
        wbc[q] = Wih[r * 10 + 9] * ks;
        bs[q]  = (bih[r] + bhh[r]) * ks;
    }
    for (int it = 0; it < 40; ++it) {
        int rid = it * 65536 + blockIdx.x * 32 + lr;
        if (rid >= N_ROWS) return;
        int b = rid & 255;
        int off = rid * 8;
        const float* p;
        if (off < NODE_ELEMS)                 p = comp + off;
        else if (off < NODE_ELEMS + POS_ELEMS) p = pos + (off - NODE_ELEMS);
        else                                   p = best + (off - NODE_ELEMS - POS_ELEMS);
        const float4* p4 = (const float4*)p;
        float4 xlo = p4[0], xhi = p4[1];
        float cv = cost[b], bv = bcost[b];
        float x[8] = {xlo.x, xlo.y, xlo.z, xlo.w, xhi.x, xhi.y, xhi.z, xhi.w};
        float g[4];
        #pragma unroll
        for (int q = 0; q < 4; ++q) {
            float a = fmaf(wc[q], cv, bs[q]);
            a = fmaf(wbc[q], bv, a);
            #pragma unroll
            for (int v = 0; v < 8; ++v) a = fmaf(wiu[q][v], x[v], a);
            g[q] = a;
        }
        float4 o = {g[0], g[1], g[2], g[3]};
        *(float4*)(gx + (size_t)rid * 32 + u * 4) = o;
    }
}

// ---------------- kernel 3: LSTM over 10000 steps (fast path) ----------------
// 32 blocks x 64 threads; lane = batch*8 + unit; gx holds x-part+bias pre-scaled.

#define DPP_GATHER() \
    int hbi = __float_as_int(hcur); \
    int d1 = __builtin_amdgcn_update_dpp(0, hbi, 0xB1, 0xF, 0xF, true); \
    int d2 = __builtin_amdgcn_update_dpp(0, hbi, 0x4E, 0xF, 0xF, true); \
    int d3 = __builtin_amdgcn_update_dpp(0, d1,  0x4E, 0xF, 0xF, true); \
    int d7 = __builtin_amdgcn_update_dpp(0, hbi, 0x141, 0xF, 0xF, true); \
    int d6 = __builtin_amdgcn_update_dpp(0, d1,  0x141, 0xF, 0xF, true); \
    int d5 = __builtin_amdgcn_update_dpp(0, d2,  0x141, 0xF, 0xF, true); \
    int d4 = __builtin_amdgcn_update_dpp(0, d3,  0x141, 0xF, 0xF, true); \
    float hv0 = hcur; \
    float hv1 = __int_as_float(d1); \
    float hv2 = __int_as_float(d2); \
    float hv3 = __int_as_float(d3); \
    float hv4 = __int_as_float(d7); \
    float hv5 = __int_as_float(d6); \
    float hv6 = __int_as_float(d5); \
    float hv7 = __int_as_float(d4);

#define ACTIVATE() \
    float si = __builtin_amdgcn_rcpf(1.f + __builtin_amdgcn_exp2f(-g0)); \
    float sf = __builtin_amdgcn_rcpf(1.f + __builtin_amdgcn_exp2f(-g1)); \
    float tg = fmaf(2.f, __builtin_amdgcn_rcpf(1.f + __builtin_amdgcn_exp2f(-g2)), -1.f); \
    float so = __builtin_amdgcn_rcpf(1.f + __builtin_amdgcn_exp2f(-g3)); \
    ccur = fmaf(sf, ccur, si * tg); \
    float tc = fmaf(2.f, __builtin_amdgcn_rcpf(1.f + __builtin_amdgcn_exp2f(ccur * -TWO_LOG2E)), -1.f); \
    hcur = so * tc;

#define LSTM2_BODY(GK) do { \
    DPP_GATHER(); \
    float g0 = fmaf(wh[0][0], hv0, GK.x); \
    float g1 = fmaf(wh[1][0], hv0, GK.y); \
    float g2 = fmaf(wh[2][0], hv0, GK.z); \
    float g3 = fmaf(wh[3][0], hv0, GK.w); \
    GK = *(const float4*)gpf; gpf += GXROW; \
    g0=fmaf(wh[0][1],hv1,g0); g1=fmaf(wh[1][1],hv1,g1); g2=fmaf(wh[2][1],hv1,g2); g3=fmaf(wh[3][1],hv1,g3); \
    g0=fmaf(wh[0][2],hv2,g0); g1=fmaf(wh[1][2],hv2,g1); g2=fmaf(wh[2][2],hv2,g2); g3=fmaf(wh[3][2],hv2,g3); \
    g0=fmaf(wh[0][3],hv3,g0); g1=fmaf(wh[1][3],hv3,g1); g2=fmaf(wh[2][3],hv3,g2); g3=fmaf(wh[3][3],hv3,g3); \
    g0=fmaf(wh[0][4],hv4,g0); g1=fmaf(wh[1][4],hv4,g1); g2=fmaf(wh[2][4],hv4,g2); g3=fmaf(wh[3][4],hv4,g3); \
    g0=fmaf(wh[0][5],hv5,g0); g1=fmaf(wh[1][5],hv5,g1); g2=fmaf(wh[2][5],hv5,g2); g3=fmaf(wh[3][5],hv5,g3); \
    g0=fmaf(wh[0][6],hv6,g0); g1=fmaf(wh[1][6],hv6,g1); g2=fmaf(wh[2][6],hv6,g2); g3=fmaf(wh[3][6],hv6,g3); \
    g0=fmaf(wh[0][7],hv7,g0); g1=fmaf(wh[1][7],hv7,g1); g2=fmaf(wh[2][7],hv7,g2); g3=fmaf(wh[3][7],hv7,g3); \
    ACTIVATE(); \
    *yp = hcur; yp += CHUNK; \
} while (0)

__global__ __launch_bounds__(64, 1) void k_lstm2(
        const float* __restrict__ gx, const float* __restrict__ h0,
        const float* __restrict__ c0, const float* __restrict__ Whh,
        float* __restrict__ ys, float* __restrict__ outhc)
{
    int lane = threadIdx.x;
    int u = lane & 7, bl = lane >> 3;
    int b = blockIdx.x * 8 + bl;
    int b8 = b * 8;

    const int xm[8] = {0, 1, 2, 3, 7, 6, 5, 4};
    float wh[4][8];
    #pragma unroll
    for (int q = 0; q < 4; ++q) {
        int r = q * 8 + u;
        float ks = (q == 2) ? TWO_LOG2E : LOG2E;
        #pragma unroll
        for (int j = 0; j < 8; ++j) wh[q][j] = Whh[r * 8 + (u ^ xm[j])] * ks;
    }
    float hcur = h0[b8 + u], ccur = c0[b8 + u];

    const float* gp = gx + (size_t)b * 32 + u * 4;
    const float* gpf = gp + 8ull * GXROW;
    float* yp = ys + b8 + u;

    float4 G0 = *(const float4*)(gp + 0ull * GXROW);
    float4 G1 = *(const float4*)(gp + 1ull * GXROW);
    float4 G2 = *(const float4*)(gp + 2ull * GXROW);
    float4 G3 = *(const float4*)(gp + 3ull * GXROW);
    float4 G4 = *(const float4*)(gp + 4ull * GXROW);
    float4 G5 = *(const float4*)(gp + 5ull * GXROW);
    float4 G6 = *(const float4*)(gp + 6ull * GXROW);
    float4 G7 = *(const float4*)(gp + 7ull * GXROW);

    for (int t = 0; t < S_TOT; t += 8) {
        LSTM2_BODY(G0);
        LSTM2_BODY(G1);
        LSTM2_BODY(G2);
        LSTM2_BODY(G3);
        LSTM2_BODY(G4);
        LSTM2_BODY(G5);
        LSTM2_BODY(G6);
        LSTM2_BODY(G7);
    }
    outhc[OUT_H + b8 + u] = hcur;
    outhc[OUT_C + b8 + u] = ccur;
}

// ---------------- kernel 3fb: LSTM fallback (R2-verified, no gx buffer) ----------------
#define FB_BODY(LO, HI, TT, SEGN, SB, YP) do { \
    float g0 = cbv[0], g1 = cbv[1], g2 = cbv[2], g3 = cbv[3]; \
    float x0=LO.x, x1=LO.y, x2=LO.z, x3=LO.w, x4=HI.x, x5=HI.y, x6=HI.z, x7=HI.w; \
    g0=fmaf(wi[0][0],x0,g0); g1=fmaf(wi[1][0],x0,g1); g2=fmaf(wi[2][0],x0,g2); g3=fmaf(wi[3][0],x0,g3); \
    g0=fmaf(wi[0][1],x1,g0); g1=fmaf(wi[1][1],x1,g1); g2=fmaf(wi[2][1],x1,g2); g3=fmaf(wi[3][1],x1,g3); \
    g0=fmaf(wi[0][2],x2,g0); g1=fmaf(wi[1][2],x2,g1); g2=fmaf(wi[2][2],x2,g2); g3=fmaf(wi[3][2],x2,g3); \
    g0=fmaf(wi[0][3],x3,g0); g1=fmaf(wi[1][3],x3,g1); g2=fmaf(wi[2][3],x3,g2); g3=fmaf(wi[3][3],x3,g3); \
    g0=fmaf(wi[0][4],x4,g0); g1=fmaf(wi[1][4],x4,g1); g2=fmaf(wi[2][4],x4,g2); g3=fmaf(wi[3][4],x4,g3); \
    g0=fmaf(wi[0][5],x5,g0); g1=fmaf(wi[1][5],x5,g1); g2=fmaf(wi[2][5],x5,g2); g3=fmaf(wi[3][5],x5,g3); \
    g0=fmaf(wi[0][6],x6,g0); g1=fmaf(wi[1][6],x6,g1); g2=fmaf(wi[2][6],x6,g2); g3=fmaf(wi[3][6],x6,g3); \
    g0=fmaf(wi[0][7],x7,g0); g1=fmaf(wi[1][7],x7,g1); g2=fmaf(wi[2][7],x7,g2); g3=fmaf(wi[3][7],x7,g3); \
    { int pf = (TT)+4; pf = (pf < (SEGN)) ? pf : ((SEGN)-1); \
      const float4* pp = (const float4*)((SB) + (size_t)pf*CHUNK); \
      LO = pp[0]; HI = pp[1]; } \
    DPP_GATHER(); \
    g0=fmaf(wh[0][0],hv0,g0); g1=fmaf(wh[1][0],hv0,g1); g2=fmaf(wh[2][0],hv0,g2); g3=fmaf(wh[3][0],hv0,g3); \
    g0=fmaf(wh[0][1],hv1,g0); g1=fmaf(wh[1][1],hv1,g1); g2=fmaf(wh[2][1],hv1,g2); g3=fmaf(wh[3][1],hv1,g3); \
    g0=fmaf(wh[0][2],hv2,g0); g1=fmaf(wh[1][2],hv2,g1); g2=fmaf(wh[2][2],hv2,g2); g3=fmaf(wh[3][2],hv2,g3); \
    g0=fmaf(wh[0][3],hv3,g0); g1=fmaf(wh[1][3],hv3,g1); g2=fmaf(wh[2][3],hv3,g2); g3=fmaf(wh[3][3],hv3,g3); \
    g0=fmaf(wh[0][4],hv4,g0); g1=fmaf(wh[1][4],hv4,g1); g2=fmaf(wh[2][4],hv4,g2); g3=fmaf(wh[3][4],hv4,g3); \
    g0=fmaf(wh[0][5],hv5,g0); g1=fmaf(wh[1][5],hv5,g1); g2=fmaf(wh[2][5],hv5,g2); g3=fmaf(wh[3][5],hv5,g3); \
    g0=fmaf(wh[0][6],hv6,g0); g1=fmaf(wh[1][6],hv6,g1); g2=fmaf(wh[2][6],hv6,g2); g3=fmaf(wh[3][6],hv6,g3); \
    g0=fmaf(wh[0][7],hv7,g0); g1=fmaf(wh[1][7],hv7,g1); g2=fmaf(wh[2][7],hv7,g2); g3=fmaf(wh[3][7],hv7,g3); \
    ACTIVATE(); \
    (YP)[(size_t)(TT)*CHUNK] = hcur; \
} while (0)

__global__ __launch_bounds__(64, 1) void k_lstm_fb(
        const float* __restrict__ comp_ws, const float* __restrict__ pos,
        const float* __restrict__ best, const float* __restrict__ cost,
        const float* __restrict__ bcost, const float* __restrict__ h0,
        const float* __restrict__ c0, const float* __restrict__ Wih,
        const float* __restrict__ Whh, const float* __restrict__ bih,
        const float* __restrict__ bhh, float* __restrict__ ys,
        float* __restrict__ outhc)
{
    int lane = threadIdx.x;
    int u = lane & 7, bl = lane >> 3;
    int b = blockIdx.x * 8 + bl;
    int b8 = b * 8;
    const int xm[8] = {0, 1, 2, 3, 7, 6, 5, 4};
    float wi[4][8], wh[4][8], cbv[4];
    #pragma unroll
    for (int q = 0; q < 4; ++q) {
        int r = q * 8 + u;
        float ks = (q == 2) ? TWO_LOG2E : LOG2E;
        #pragma unroll
        for (int v = 0; v < 8; ++v) wi[q][v] = Wih[r * 10 + v] * ks;
        #pragma unroll
        for (int j = 0; j < 8; ++j) wh[q][j] = Whh[r * 8 + (u ^ xm[j])] * ks;
        cbv[q] = (bih[r] + bhh[r] + Wih[r * 10 + 8] * cost[b] + Wih[r * 10 + 9] * bcost[b]) * ks;
    }
    float hcur = h0[b8 + u], ccur = c0[b8 + u];
    #define FB_RUN(BASE, YSOFF, SEGN) do { \
        const float* sb = (BASE) + b8; \
        float* yp = ys + (size_t)(YSOFF)*CHUNK + b8 + u; \
        float4 L0,H0,L1,H1,L2,H2,L3,H3; \
        { const float4* p=(const float4*)(sb + 0*CHUNK); L0=p[0]; H0=p[1]; } \
        { const float4* p=(const float4*)(sb + 1*CHUNK); L1=p[0]; H1=p[1]; } \
        { const float4* p=(const float4*)(sb + 2*CHUNK); L2=p[0]; H2=p[1]; } \
        { const float4* p=(const float4*)(sb + 3*CHUNK); L3=p[0]; H3=p[1]; } \
        for (int t = 0; t < (SEGN); t += 4) { \
            FB_BODY(L0, H0, t+0, SEGN, sb, yp); \
            FB_BODY(L1, H1, t+1, SEGN, sb, yp); \
            FB_BODY(L2, H2, t+2, SEGN, sb, yp); \
            FB_BODY(L3, H3, t+3, SEGN, sb, yp); \
        } \
    } while (0)
    FB_RUN(comp_ws, 0,    5000);
    FB_RUN(pos,     5000, 2500);
    FB_RUN(best,    7500, 2500);
    outhc[OUT_H + b8 + u] = hcur;
    outhc[OUT_C + b8 + u] = ccur;
}

// ---------------- kernel 4: softmax rows + attn @ V (denominator folded) ----------------
__global__ __launch_bounds__(256) void k_softmax_av(const float* __restrict__ ys,
        const float* __restrict__ V, float* __restrict__ heads)
{
    __shared__ float P[Gn * 101];
    __shared__ float Vs[Gn * 33];
    __shared__ float pm[256];
    __shared__ float rmaxs[Gn];
    __shared__ float rinvs[Gn];
    const float* ysrc = ys + (size_t)blockIdx.x * GG;
    for (int idx = threadIdx.x; idx < GG; idx += 256) {
        int i = idx / 100, j = idx - i * 100;
        P[i * 101 + j] = ysrc[idx];
    }
    const float* vsrc = V + (size_t)blockIdx.x * (Gn * KD);
    for (int idx = threadIdx.x; idx < Gn * KD; idx += 256) {
        int i = idx >> 5, d = idx & 31;
        Vs[i * 33 + d] = vsrc[idx];
    }
    __syncthreads();
    int t = threadIdx.x;
    if (t < 200) {
        const float* row = P + (t >> 1) * 101 + (t & 1) * 50;
        float m = -1e30f;
        #pragma unroll 5
        for (int j = 0; j < 50; ++j) m = fmaxf(m, row[j]);
        pm[t] = m;
    }
    __syncthreads();
    if (t < Gn) rmaxs[t] = fmaxf(pm[2 * t], pm[2 * t + 1]);
    __syncthreads();
    if (t < 200) {
        float* row = P + (t >> 1) * 101 + (t & 1) * 50;
        float m = rmaxs[t >> 1];
        float ss = 0.f;
        #pragma unroll 5
        for (int j = 0; j < 50; ++j) {
            float e = __builtin_amdgcn_exp2f((row[j] - m) * LOG2E);
            row[j] = e; ss += e;
        }
        pm[t] = ss;
    }
    __syncthreads();
    if (t < Gn) rinvs[t] = __builtin_amdgcn_rcpf(pm[2 * t] + pm[2 * t + 1]);
    __syncthreads();
    int d = t & 31, ii = t >> 5;
    float* hb = heads + (size_t)blockIdx.x * (Gn * KD);
    for (int i0 = 0; i0 < Gn; i0 += 8) {
        int i = i0 + ii;
        if (i < Gn) {
            float acc = 0.f;
            #pragma unroll 4
            for (int j = 0; j < Gn; ++j)
                acc = fmaf(P[i * 101 + j], Vs[j * 33 + d], acc);
            hb[i * KD + d] = acc * rinvs[i];
        }
    }
}

// ---------------- kernel 5: output projection ----------------
// grid 256*13; block = (b, p); out[b,i,e] = sum_{h,d} heads[h,b,i,d]*Wo[h,d,e]
__global__ __launch_bounds__(256) void k_outproj(const float* __restrict__ heads,
        const float* __restrict__ Wo, float* __restrict__ out)
{
    int b = blockIdx.x / 13, p = blockIdx.x % 13;
    int e = threadIdx.x & 127, half = threadIdx.x >> 7;
    int r0 = p * 8 + half * 4;
    float acc0 = 0.f, acc1 = 0.f, acc2 = 0.f, acc3 = 0.f;
    for (int h = 0; h < NH; ++h) {
        const float* hs = heads + (size_t)h * (256 * Gn * KD) + (size_t)b * (Gn * KD);
        const float* wsrc = Wo + h * (KD * IND);
        #pragma unroll 8
        for (int d = 0; d < KD; ++d) {
            float w = wsrc[d * IND + e];
            if (r0 + 3 < Gn) {
                acc0 = fmaf(hs[(r0 + 0) * KD + d], w, acc0);
                acc1 = fmaf(hs[(r0 + 1) * KD + d], w, acc1);
                acc2 = fmaf(hs[(r0 + 2) * KD + d], w, acc2);
                acc3 = fmaf(hs[(r0 + 3) * KD + d], w, acc3);
            } else {
                if (r0 + 0 < Gn) acc0 = fmaf(hs[(r0 + 0) * KD + d], w, acc0);
                if (r0 + 1 < Gn) acc1 = fmaf(hs[(r0 + 1) * KD + d], w, acc1);
                if (r0 + 2 < Gn) acc2 = fmaf(hs[(r0 + 2) * KD + d], w, acc2);
                if (r0 + 3 < Gn) acc3 = fmaf(hs[(r0 + 3) * KD + d], w, acc3);
            }
        }
    }
    if (r0 + 0 < Gn) out[((size_t)b * Gn + r0 + 0) * IND + e] = acc0;
    if (r0 + 1 < Gn) out[((size_t)b * Gn + r0 + 1) * IND + e] = acc1;
    if (r0 + 2 < Gn) out[((size_t)b * Gn + r0 + 2) * IND + e] = acc2;
    if (r0 + 3 < Gn) out[((size_t)b * Gn + r0 + 3) * IND + e] = acc3;
}

extern "C" void kernel_launch(void* const* d_in, const int* in_sizes, int n_in,
                              void* d_out, int out_size, void* d_ws, size_t ws_size,
                              hipStream_t stream) {
    const float* X     = (const float*)d_in[0];
    const float* pos   = (const float*)d_in[1];
    const float* best  = (const float*)d_in[2];
    const float* cost  = (const float*)d_in[3];
    const float* bcost = (const float*)d_in[4];
    const float* h0    = (const float*)d_in[5];
    const float* c0    = (const float*)d_in[6];
    const float* Wq    = (const float*)d_in[7];
    const float* Wk    = (const float*)d_in[8];
    const float* Wv    = (const float*)d_in[9];
    const float* Wo    = (const float*)d_in[10];
    const float* Wih   = (const float*)d_in[11];
    const float* Whh   = (const float*)d_in[12];
    const float* bih   = (const float*)d_in[13];
    const float* bhh   = (const float*)d_in[14];
    float* out = (float*)d_out;
    char* ws = (char*)d_ws;

    if (ws_size < WS_FB) {
        k_wsfail<<<1, 1, 0, stream>>>(out, (float)ws_size);
        return;
    }

    float* comp   = (float*)(ws);
    float* Vw     = (float*)(ws + V_OFF);
    float* ysw    = (float*)(ws + YS_OFF);
    float* headsw = (float*)(ws);  // reuse comp region (consumed before kernel 4)

    k_qk_comp<<<1024, 256, 0, stream>>>(X, Wq, Wk, comp);
    k_vproj<<<2048, 256, 0, stream>>>(X, Wv, Vw);
    if (ws_size >= WS_FAST) {
        float* gxw = (float*)(ws + GX_OFF);
        k_gx<<<2048, 256, 0, stream>>>(comp, pos, best, cost, bcost, Wih, bih, bhh, gxw);
        k_lstm2<<<32, 64, 0, stream>>>(gxw, h0, c0, Whh, ysw, out);
    } else {
        k_lstm_fb<<<32, 64, 0, stream>>>(comp, pos, best, cost, bcost, h0, c0,
                                         Wih, Whh, bih, bhh, ysw, out);
    }
    k_softmax_av<<<2048, 256, 0, stream>>>(ysw, Vw, headsw);
    k_outproj<<<256 * 13, 256, 0, stream>>>(headsw, Wo, out);
}

// Round 5
// 2192.423 us; speedup vs baseline: 1.9023x; 1.2662x over previous
//
#include <hip/hip_runtime.h>

#define Bsz 256
#define Gn 100
#define GG 10000
#define IND 128
#define KD 32
#define NH 8
#define S_TOT 10000
#define CHUNK 2048               // Bsz*NH (elements per step)
#define NODE_ELEMS 10240000      // 4*Bsz*GG
#define P1_ELEMS   5120000       // pos elements (2 heads)
#define NORMC 0.17677669529663687f
#define LOG2E 1.4426950408889634f
#define TWO_LOG2E 2.8853900817779268f

// ws layout (bytes): [ys f32 81,920,000][V f32 26,214,400][xh f16 40,960,000]
#define V_OFF    81920000ull
#define XH_OFF   108134400ull
#define HEADS_OFF XH_OFF          // xh dead after LSTM; heads reuses it
#define WS_MIN   149094400ull

// out layout (floats)
#define OUT_H 3276800
#define OUT_C 3278848

typedef _Float16 half2_t __attribute__((ext_vector_type(2)));
typedef _Float16 half4_t __attribute__((ext_vector_type(4)));

#if defined(__has_builtin)
#if __has_builtin(__builtin_amdgcn_fdot2)
#define HAVE_FDOT2 1
#endif
#endif

#ifdef HAVE_FDOT2
#define FDOT2(a,b,c) __builtin_amdgcn_fdot2((a),(b),(c),false)
#else
static __device__ __forceinline__ float fdot2_sw(half2_t a, half2_t b, float c){
    return fmaf((float)a[1], (float)b[1], fmaf((float)a[0], (float)b[0], c));
}
#define FDOT2(a,b,c) fdot2_sw((a),(b),(c))
#endif

#define PKRTZ(a,b) __builtin_bit_cast(half2_t, __builtin_amdgcn_cvt_pkrtz((a),(b)))

__global__ void k_wsfail(float* out, float v) { out[0] = v; }

// ---------------- kernel 1: Q/K projection + node compatibility (f16 out) ----------------
__global__ __launch_bounds__(256) void k_qk_comp(const float* __restrict__ X,
        const float* __restrict__ Wq, const float* __restrict__ Wk,
        _Float16* __restrict__ xh)
{
    int h = blockIdx.x >> 8, b = blockIdx.x & 255;
    __shared__ float Qs[Gn * 33];
    __shared__ float Ks[Gn * 33];
    const float* Xb = X + (size_t)b * Gn * IND;
    const float* wq = Wq + h * IND * KD;
    const float* wk = Wk + h * IND * KD;
    int k = threadIdx.x & 31, ii = threadIdx.x >> 5;
    for (int i0 = 0; i0 < Gn; i0 += 8) {
        int i = i0 + ii;
        if (i < Gn) {
            float aq = 0.f, ak = 0.f;
            const float* xr = Xb + i * IND;
            #pragma unroll 8
            for (int c = 0; c < IND; ++c) {
                float x = xr[c];
                aq = fmaf(x, wq[c * KD + k], aq);
                ak = fmaf(x, wk[c * KD + k], ak);
            }
            Qs[i * 33 + k] = aq;
            Ks[i * 33 + k] = ak;
        }
    }
    __syncthreads();
    _Float16* cb = xh + (size_t)blockIdx.x * GG;
    for (int idx = threadIdx.x; idx < GG; idx += 256) {
        int i = idx / 100, j = idx - i * 100;
        float acc = 0.f;
        #pragma unroll
        for (int kk = 0; kk < KD; ++kk)
            acc = fmaf(Qs[i * 33 + kk], Ks[j * 33 + kk], acc);
        cb[idx] = (_Float16)(acc * NORMC);
    }
}

// ---------------- kernel 1b: cast pos/best -> f16 tail of xh ----------------
__global__ __launch_bounds__(256) void k_cast(const float* __restrict__ pos,
        const float* __restrict__ best, _Float16* __restrict__ xh)
{
    const size_t TOT4 = (size_t)(2 * P1_ELEMS) / 4;   // 2,560,000 float4s
    const size_t P14 = P1_ELEMS / 4;
    for (size_t i = (size_t)blockIdx.x * 256 + threadIdx.x; i < TOT4; i += 2048 * 256) {
        float4 v = (i < P14) ? ((const float4*)pos)[i] : ((const float4*)best)[i - P14];
        half4_t o = {(_Float16)v.x, (_Float16)v.y, (_Float16)v.z, (_Float16)v.w};
        *(half4_t*)(xh + NODE_ELEMS + i * 4) = o;
    }
}

// ---------------- kernel 2: V projection ----------------
__global__ __launch_bounds__(256) void k_vproj(const float* __restrict__ X,
        const float* __restrict__ Wv, float* __restrict__ V)
{
    int h = blockIdx.x >> 8, b = blockIdx.x & 255;
    __shared__ float Xs[Gn * IND];
    const float4* X4 = (const float4*)(X + (size_t)b * Gn * IND);
    float4* Xs4 = (float4*)Xs;
    for (int i = threadIdx.x; i < Gn * IND / 4; i += 256) Xs4[i] = X4[i];
    __syncthreads();
    const float* wv = Wv + h * IND * KD;
    int k = threadIdx.x & 31, ii = threadIdx.x >> 5;
    float* vb = V + (size_t)blockIdx.x * (Gn * KD);
    for (int i0 = 0; i0 < Gn; i0 += 8) {
        int i = i0 + ii;
        if (i < Gn) {
            float a = 0.f;
            #pragma unroll 8
            for (int c = 0; c < IND; ++c)
                a = fmaf(Xs[i * IND + c], wv[c * KD + k], a);
            vb[i * KD + k] = a;
        }
    }
}

// ---------------- kernel 3: LSTM over 10000 steps (f16 dot2) ----------------
// 32 blocks x 64 threads; lane = batch*8 + unit; x-stream packed f16.

#define DPP_GATHER() \
    int hbi = __float_as_int(hcur); \
    int d1 = __builtin_amdgcn_update_dpp(0, hbi, 0xB1, 0xF, 0xF, true); \
    int d2 = __builtin_amdgcn_update_dpp(0, hbi, 0x4E, 0xF, 0xF, true); \
    int d3 = __builtin_amdgcn_update_dpp(0, d1,  0x4E, 0xF, 0xF, true); \
    int d7 = __builtin_amdgcn_update_dpp(0, hbi, 0x141, 0xF, 0xF, true); \
    int d6 = __builtin_amdgcn_update_dpp(0, d1,  0x141, 0xF, 0xF, true); \
    int d5 = __builtin_amdgcn_update_dpp(0, d2,  0x141, 0xF, 0xF, true); \
    int d4 = __builtin_amdgcn_update_dpp(0, d3,  0x141, 0xF, 0xF, true); \
    float hv0 = hcur; \
    float hv1 = __int_as_float(d1); \
    float hv2 = __int_as_float(d2); \
    float hv3 = __int_as_float(d3); \
    float hv4 = __int_as_float(d7); \
    float hv5 = __int_as_float(d6); \
    float hv6 = __int_as_float(d5); \
    float hv7 = __int_as_float(d4);

#define ACTIVATE() \
    float si = __builtin_amdgcn_rcpf(1.f + __builtin_amdgcn_exp2f(-g0)); \
    float sf = __builtin_amdgcn_rcpf(1.f + __builtin_amdgcn_exp2f(-g1)); \
    float tg = fmaf(2.f, __builtin_amdgcn_rcpf(1.f + __builtin_amdgcn_exp2f(-g2)), -1.f); \
    float so = __builtin_amdgcn_rcpf(1.f + __builtin_amdgcn_exp2f(-g3)); \
    ccur = fmaf(sf, ccur, si * tg); \
    float tc = fmaf(2.f, __builtin_amdgcn_rcpf(1.f + __builtin_amdgcn_exp2f(ccur * -TWO_LOG2E)), -1.f); \
    hcur = so * tc;

#define XDOTS(SL) \
    half2_t xp0 = __builtin_bit_cast(half2_t, SL.x); \
    half2_t xp1 = __builtin_bit_cast(half2_t, SL.y); \
    half2_t xp2 = __builtin_bit_cast(half2_t, SL.z); \
    half2_t xp3 = __builtin_bit_cast(half2_t, SL.w); \
    float g0 = FDOT2(wi_pk[0][0], xp0, cbv[0]); \
    float g1 = FDOT2(wi_pk[1][0], xp0, cbv[1]); \
    float g2 = FDOT2(wi_pk[2][0], xp0, cbv[2]); \
    float g3 = FDOT2(wi_pk[3][0], xp0, cbv[3]); \
    g0 = FDOT2(wi_pk[0][1], xp1, g0); g1 = FDOT2(wi_pk[1][1], xp1, g1); \
    g2 = FDOT2(wi_pk[2][1], xp1, g2); g3 = FDOT2(wi_pk[3][1], xp1, g3); \
    g0 = FDOT2(wi_pk[0][2], xp2, g0); g1 = FDOT2(wi_pk[1][2], xp2, g1); \
    g2 = FDOT2(wi_pk[2][2], xp2, g2); g3 = FDOT2(wi_pk[3][2], xp2, g3); \
    g0 = FDOT2(wi_pk[0][3], xp3, g0); g1 = FDOT2(wi_pk[1][3], xp3, g1); \
    g2 = FDOT2(wi_pk[2][3], xp3, g2); g3 = FDOT2(wi_pk[3][3], xp3, g3);

#define HDOTS() \
    half2_t ph0 = PKRTZ(hv0, hv1); \
    half2_t ph1 = PKRTZ(hv2, hv3); \
    half2_t ph2 = PKRTZ(hv4, hv5); \
    half2_t ph3 = PKRTZ(hv6, hv7); \
    g0 = FDOT2(wh_pk[0][0], ph0, g0); g1 = FDOT2(wh_pk[1][0], ph0, g1); \
    g2 = FDOT2(wh_pk[2][0], ph0, g2); g3 = FDOT2(wh_pk[3][0], ph0, g3); \
    g0 = FDOT2(wh_pk[0][1], ph1, g0); g1 = FDOT2(wh_pk[1][1], ph1, g1); \
    g2 = FDOT2(wh_pk[2][1], ph1, g2); g3 = FDOT2(wh_pk[3][1], ph1, g3); \
    g0 = FDOT2(wh_pk[0][2], ph2, g0); g1 = FDOT2(wh_pk[1][2], ph2, g1); \
    g2 = FDOT2(wh_pk[2][2], ph2, g2); g3 = FDOT2(wh_pk[3][2], ph2, g3); \
    g0 = FDOT2(wh_pk[0][3], ph3, g0); g1 = FDOT2(wh_pk[1][3], ph3, g1); \
    g2 = FDOT2(wh_pk[2][3], ph3, g2); g3 = FDOT2(wh_pk[3][3], ph3, g3);

#define BODY_PF(SL) do { \
    XDOTS(SL); \
    SL = *(const int4*)gnext; gnext += CHUNK; \
    DPP_GATHER(); \
    HDOTS(); \
    ACTIVATE(); \
    *yp = hcur; yp += CHUNK; \
} while (0)

#define BODY_NT(SL) do { \
    XDOTS(SL); \
    DPP_GATHER(); \
    HDOTS(); \
    ACTIVATE(); \
    *yp = hcur; yp += CHUNK; \
} while (0)

__global__ __launch_bounds__(64, 1) void k_lstm3(
        const _Float16* __restrict__ xh, const float* __restrict__ cost,
        const float* __restrict__ bcost, const float* __restrict__ h0,
        const float* __restrict__ c0, const float* __restrict__ Wih,
        const float* __restrict__ Whh, const float* __restrict__ bih,
        const float* __restrict__ bhh, float* __restrict__ ys,
        float* __restrict__ outhc)
{
    int lane = threadIdx.x;
    int u = lane & 7, bl = lane >> 3;
    int b = blockIdx.x * 8 + bl;
    int b8 = b * 8;

    const int xm[8] = {0, 1, 2, 3, 7, 6, 5, 4};
    half2_t wi_pk[4][4], wh_pk[4][4];
    float cbv[4];
    #pragma unroll
    for (int q = 0; q < 4; ++q) {
        int r = q * 8 + u;
        float ks = (q == 2) ? TWO_LOG2E : LOG2E;
        #pragma unroll
        for (int p = 0; p < 4; ++p) {
            half2_t wi = {(_Float16)(Wih[r * 10 + 2 * p] * ks),
                          (_Float16)(Wih[r * 10 + 2 * p + 1] * ks)};
            wi_pk[q][p] = wi;
            half2_t wh = {(_Float16)(Whh[r * 8 + (u ^ xm[2 * p])] * ks),
                          (_Float16)(Whh[r * 8 + (u ^ xm[2 * p + 1])] * ks)};
            wh_pk[q][p] = wh;
        }
        cbv[q] = (bih[r] + bhh[r] + Wih[r * 10 + 8] * cost[b] + Wih[r * 10 + 9] * bcost[b]) * ks;
    }
    float hcur = h0[b8 + u], ccur = c0[b8 + u];

    const _Float16* gp = xh + b8;
    int4 S0 = *(const int4*)(gp + 0 * CHUNK);
    int4 S1 = *(const int4*)(gp + 1 * CHUNK);
    int4 S2 = *(const int4*)(gp + 2 * CHUNK);
    int4 S3 = *(const int4*)(gp + 3 * CHUNK);
    int4 S4 = *(const int4*)(gp + 4 * CHUNK);
    int4 S5 = *(const int4*)(gp + 5 * CHUNK);
    int4 S6 = *(const int4*)(gp + 6 * CHUNK);
    int4 S7 = *(const int4*)(gp + 7 * CHUNK);
    const _Float16* gnext = gp + 8 * CHUNK;
    float* yp = ys + b8 + u;

    for (int t = 0; t < 9992; t += 8) {
        BODY_PF(S0);
        BODY_PF(S1);
        BODY_PF(S2);
        BODY_PF(S3);
        BODY_PF(S4);
        BODY_PF(S5);
        BODY_PF(S6);
        BODY_PF(S7);
    }
    BODY_NT(S0);
    BODY_NT(S1);
    BODY_NT(S2);
    BODY_NT(S3);
    BODY_NT(S4);
    BODY_NT(S5);
    BODY_NT(S6);
    BODY_NT(S7);

    outhc[OUT_H + b8 + u] = hcur;
    outhc[OUT_C + b8 + u] = ccur;
}

// ---------------- kernel 4: softmax rows + attn @ V (denominator folded) ----------------
__global__ __launch_bounds__(256) void k_softmax_av(const float* __restrict__ ys,
        const float* __restrict__ V, float* __restrict__ heads)
{
    __shared__ float P[Gn * 101];
    __shared__ float Vs[Gn * 33];
    __shared__ float pm[256];
    __shared__ float rmaxs[Gn];
    __shared__ float rinvs[Gn];
    const float* ysrc = ys + (size_t)blockIdx.x * GG;
    for (int idx = threadIdx.x; idx < GG; idx += 256) {
        int i = idx / 100, j = idx - i * 100;
        P[i * 101 + j] = ysrc[idx];
    }
    const float* vsrc = V + (size_t)blockIdx.x * (Gn * KD);
    for (int idx = threadIdx.x; idx < Gn * KD; idx += 256) {
        int i = idx >> 5, d = idx & 31;
        Vs[i * 33 + d] = vsrc[idx];
    }
    __syncthreads();
    int t = threadIdx.x;
    if (t < 200) {
        const float* row = P + (t >> 1) * 101 + (t & 1) * 50;
        float m = -1e30f;
        #pragma unroll 5
        for (int j = 0; j < 50; ++j) m = fmaxf(m, row[j]);
        pm[t] = m;
    }
    __syncthreads();
    if (t < Gn) rmaxs[t] = fmaxf(pm[2 * t], pm[2 * t + 1]);
    __syncthreads();
    if (t < 200) {
        float* row = P + (t >> 1) * 101 + (t & 1) * 50;
        float m = rmaxs[t >> 1];
        float ss = 0.f;
        #pragma unroll 5
        for (int j = 0; j < 50; ++j) {
            float e = __builtin_amdgcn_exp2f((row[j] - m) * LOG2E);
            row[j] = e; ss += e;
        }
        pm[t] = ss;
    }
    __syncthreads();
    if (t < Gn) rinvs[t] = __builtin_amdgcn_rcpf(pm[2 * t] + pm[2 * t + 1]);
    __syncthreads();
    int d = t & 31, ii = t >> 5;
    float* hb = heads + (size_t)blockIdx.x * (Gn * KD);
    for (int i0 = 0; i0 < Gn; i0 += 8) {
        int i = i0 + ii;
        if (i < Gn) {
            float acc = 0.f;
            #pragma unroll 4
            for (int j = 0; j < Gn; ++j)
                acc = fmaf(P[i * 101 + j], Vs[j * 33 + d], acc);
            hb[i * KD + d] = acc * rinvs[i];
        }
    }
}

// ---------------- kernel 5: output projection ----------------
__global__ __launch_bounds__(256) void k_outproj(const float* __restrict__ heads,
        const float* __restrict__ Wo, float* __restrict__ out)
{
    int b = blockIdx.x / 13, p = blockIdx.x % 13;
    int e = threadIdx.x & 127, half = threadIdx.x >> 7;
    int r0 = p * 8 + half * 4;
    float acc0 = 0.f, acc1 = 0.f, acc2 = 0.f, acc3 = 0.f;
    for (int h = 0; h < NH; ++h) {
        const float* hs = heads + (size_t)h * (256 * Gn * KD) + (size_t)b * (Gn * KD);
        const float* wsrc = Wo + h * (KD * IND);
        #pragma unroll 8
        for (int d = 0; d < KD; ++d) {
            float w = wsrc[d * IND + e];
            if (r0 + 3 < Gn) {
                acc0 = fmaf(hs[(r0 + 0) * KD + d], w, acc0);
                acc1 = fmaf(hs[(r0 + 1) * KD + d], w, acc1);
                acc2 = fmaf(hs[(r0 + 2) * KD + d], w, acc2);
                acc3 = fmaf(hs[(r0 + 3) * KD + d], w, acc3);
            } else {
                if (r0 + 0 < Gn) acc0 = fmaf(hs[(r0 + 0) * KD + d], w, acc0);
                if (r0 + 1 < Gn) acc1 = fmaf(hs[(r0 + 1) * KD + d], w, acc1);
                if (r0 + 2 < Gn) acc2 = fmaf(hs[(r0 + 2) * KD + d], w, acc2);
                if (r0 + 3 < Gn) acc3 = fmaf(hs[(r0 + 3) * KD + d], w, acc3);
            }
        }
    }
    if (r0 + 0 < Gn) out[((size_t)b * Gn + r0 + 0) * IND + e] = acc0;
    if (r0 + 1 < Gn) out[((size_t)b * Gn + r0 + 1) * IND + e] = acc1;
    if (r0 + 2 < Gn) out[((size_t)b * Gn + r0 + 2) * IND + e] = acc2;
    if (r0 + 3 < Gn) out[((size_t)b * Gn + r0 + 3) * IND + e] = acc3;
}

extern "C" void kernel_launch(void* const* d_in, const int* in_sizes, int n_in,
                              void* d_out, int out_size, void* d_ws, size_t ws_size,
                              hipStream_t stream) {
    const float* X     = (const float*)d_in[0];
    const float* pos   = (const float*)d_in[1];
    const float* best  = (const float*)d_in[2];
    const float* cost  = (const float*)d_in[3];
    const float* bcost = (const float*)d_in[4];
    const float* h0    = (const float*)d_in[5];
    const float* c0    = (const float*)d_in[6];
    const float* Wq    = (const float*)d_in[7];
    const float* Wk    = (const float*)d_in[8];
    const float* Wv    = (const float*)d_in[9];
    const float* Wo    = (const float*)d_in[10];
    const float* Wih   = (const float*)d_in[11];
    const float* Whh   = (const float*)d_in[12];
    const float* bih   = (const float*)d_in[13];
    const float* bhh   = (const float*)d_in[14];
    float* out = (float*)d_out;
    char* ws = (char*)d_ws;

    if (ws_size < WS_MIN) {
        k_wsfail<<<1, 1, 0, stream>>>(out, (float)ws_size);
        return;
    }

    float* ysw      = (float*)(ws);
    float* Vw       = (float*)(ws + V_OFF);
    _Float16* xhw   = (_Float16*)(ws + XH_OFF);
    float* headsw   = (float*)(ws + HEADS_OFF);   // xh region, dead after LSTM

    k_qk_comp<<<1024, 256, 0, stream>>>(X, Wq, Wk, xhw);
    k_cast<<<2048, 256, 0, stream>>>(pos, best, xhw);
    k_vproj<<<2048, 256, 0, stream>>>(X, Wv, Vw);
    k_lstm3<<<32, 64, 0, stream>>>(xhw, cost, bcost, h0, c0,
                                   Wih, Whh, bih, bhh, ysw, out);
    k_softmax_av<<<2048, 256, 0, stream>>>(ysw, Vw, headsw);
    k_outproj<<<256 * 13, 256, 0, stream>>>(headsw, Wo, out);
}

// Round 6
// 1973.406 us; speedup vs baseline: 2.1134x; 1.1110x over previous
//
#include <hip/hip_runtime.h>

#define Bsz 256
#define Gn 100
#define GG 10000
#define IND 128
#define KD 32
#define NH 8
#define S_TOT 10000
#define CHUNK 2048               // Bsz*NH (elements per step)
#define NODE_ELEMS 10240000      // 4*Bsz*GG
#define P1_ELEMS   5120000       // pos elements (2 heads)
#define NORMC 0.17677669529663687f
#define LOG2E 1.4426950408889634f
#define TWO_LOG2E 2.8853900817779268f

// ws layout (bytes): [ys f32 81,920,000][V f32 26,214,400][xh f16 40,960,000]
#define V_OFF    81920000ull
#define XH_OFF   108134400ull
#define HEADS_OFF XH_OFF          // xh dead after LSTM; heads reuses it
#define WS_MIN   149094400ull

// out layout (floats)
#define OUT_H 3276800
#define OUT_C 3278848

typedef _Float16 half2_t __attribute__((ext_vector_type(2)));
typedef _Float16 half4_t __attribute__((ext_vector_type(4)));

#define FDOT2(a,b,c) __builtin_amdgcn_fdot2((a),(b),(c),false)
#define PKRTZ(a,b) __builtin_bit_cast(half2_t, __builtin_amdgcn_cvt_pkrtz((a),(b)))

__global__ void k_wsfail(float* out, float v) { out[0] = v; }

// ---------------- kernel 1: Q/K projection + node compatibility (f16 out) ----------------
__global__ __launch_bounds__(256) void k_qk_comp(const float* __restrict__ X,
        const float* __restrict__ Wq, const float* __restrict__ Wk,
        _Float16* __restrict__ xh)
{
    int h = blockIdx.x >> 8, b = blockIdx.x & 255;
    __shared__ float Qs[Gn * 33];
    __shared__ float Ks[Gn * 33];
    const float* Xb = X + (size_t)b * Gn * IND;
    const float* wq = Wq + h * IND * KD;
    const float* wk = Wk + h * IND * KD;
    int k = threadIdx.x & 31, ii = threadIdx.x >> 5;
    for (int i0 = 0; i0 < Gn; i0 += 8) {
        int i = i0 + ii;
        if (i < Gn) {
            float aq = 0.f, ak = 0.f;
            const float* xr = Xb + i * IND;
            #pragma unroll 8
            for (int c = 0; c < IND; ++c) {
                float x = xr[c];
                aq = fmaf(x, wq[c * KD + k], aq);
                ak = fmaf(x, wk[c * KD + k], ak);
            }
            Qs[i * 33 + k] = aq;
            Ks[i * 33 + k] = ak;
        }
    }
    __syncthreads();
    _Float16* cb = xh + (size_t)blockIdx.x * GG;
    for (int idx = threadIdx.x; idx < GG; idx += 256) {
        int i = idx / 100, j = idx - i * 100;
        float acc = 0.f;
        #pragma unroll
        for (int kk = 0; kk < KD; ++kk)
            acc = fmaf(Qs[i * 33 + kk], Ks[j * 33 + kk], acc);
        cb[idx] = (_Float16)(acc * NORMC);
    }
}

// ---------------- kernel 1b: cast pos/best -> f16 tail of xh ----------------
__global__ __launch_bounds__(256) void k_cast(const float* __restrict__ pos,
        const float* __restrict__ best, _Float16* __restrict__ xh)
{
    const size_t TOT4 = (size_t)(2 * P1_ELEMS) / 4;   // 2,560,000 float4s
    const size_t P14 = P1_ELEMS / 4;
    for (size_t i = (size_t)blockIdx.x * 256 + threadIdx.x; i < TOT4; i += 2048 * 256) {
        float4 v = (i < P14) ? ((const float4*)pos)[i] : ((const float4*)best)[i - P14];
        half4_t o = {(_Float16)v.x, (_Float16)v.y, (_Float16)v.z, (_Float16)v.w};
        *(half4_t*)(xh + NODE_ELEMS + i * 4) = o;
    }
}

// ---------------- kernel 2: V projection ----------------
__global__ __launch_bounds__(256) void k_vproj(const float* __restrict__ X,
        const float* __restrict__ Wv, float* __restrict__ V)
{
    int h = blockIdx.x >> 8, b = blockIdx.x & 255;
    __shared__ float Xs[Gn * IND];
    const float4* X4 = (const float4*)(X + (size_t)b * Gn * IND);
    float4* Xs4 = (float4*)Xs;
    for (int i = threadIdx.x; i < Gn * IND / 4; i += 256) Xs4[i] = X4[i];
    __syncthreads();
    const float* wv = Wv + h * IND * KD;
    int k = threadIdx.x & 31, ii = threadIdx.x >> 5;
    float* vb = V + (size_t)blockIdx.x * (Gn * KD);
    for (int i0 = 0; i0 < Gn; i0 += 8) {
        int i = i0 + ii;
        if (i < Gn) {
            float a = 0.f;
            #pragma unroll 8
            for (int c = 0; c < IND; ++c)
                a = fmaf(Xs[i * IND + c], wv[c * KD + k], a);
            vb[i * KD + k] = a;
        }
    }
}

// ---------------- kernel 3: LSTM, 16 lanes/batch, gates split 2+2 ----------------
// 64 blocks x 64 threads; lane = bw*16 + p*8 + u.
// p=0 owns gates {i,f}; p=1 owns {g,o}. Both halves compute identical c,h.

#define DPP(ctl, x) __builtin_amdgcn_update_dpp(0, (x), (ctl), 0xF, 0xF, true)

#define DPP_GATHER() \
    int hbi = __float_as_int(hcur); \
    int d1 = DPP(0xB1, hbi); \
    int d2 = DPP(0x4E, hbi); \
    int d3 = DPP(0x4E, d1); \
    int d7 = DPP(0x141, hbi); \
    int d6 = DPP(0x141, d1); \
    int d5 = DPP(0x141, d2); \
    int d4 = DPP(0x141, d3); \
    float hv0 = hcur; \
    float hv1 = __int_as_float(d1); \
    float hv2 = __int_as_float(d2); \
    float hv3 = __int_as_float(d3); \
    float hv4 = __int_as_float(d7); \
    float hv5 = __int_as_float(d6); \
    float hv6 = __int_as_float(d5); \
    float hv7 = __int_as_float(d4);

#define XDOTS16(SL) \
    half2_t xp0 = __builtin_bit_cast(half2_t, SL.x); \
    half2_t xp1 = __builtin_bit_cast(half2_t, SL.y); \
    half2_t xp2 = __builtin_bit_cast(half2_t, SL.z); \
    half2_t xp3 = __builtin_bit_cast(half2_t, SL.w); \
    float ga = FDOT2(wi_pk[0][0], xp0, cbv[0]); \
    float gb = FDOT2(wi_pk[1][0], xp0, cbv[1]); \
    ga = FDOT2(wi_pk[0][1], xp1, ga); gb = FDOT2(wi_pk[1][1], xp1, gb); \
    ga = FDOT2(wi_pk[0][2], xp2, ga); gb = FDOT2(wi_pk[1][2], xp2, gb); \
    ga = FDOT2(wi_pk[0][3], xp3, ga); gb = FDOT2(wi_pk[1][3], xp3, gb);

#define HDOTS16() \
    half2_t ph0 = PKRTZ(hv0, hv1); \
    half2_t ph1 = PKRTZ(hv2, hv3); \
    half2_t ph2 = PKRTZ(hv4, hv5); \
    half2_t ph3 = PKRTZ(hv6, hv7); \
    ga = FDOT2(wh_pk[0][0], ph0, ga); gb = FDOT2(wh_pk[1][0], ph0, gb); \
    ga = FDOT2(wh_pk[0][1], ph1, ga); gb = FDOT2(wh_pk[1][1], ph1, gb); \
    ga = FDOT2(wh_pk[0][2], ph2, ga); gb = FDOT2(wh_pk[1][2], ph2, gb); \
    ga = FDOT2(wh_pk[0][3], ph3, ga); gb = FDOT2(wh_pk[1][3], ph3, gb);

#define ACT16() \
    float A = __builtin_amdgcn_rcpf(1.f + __builtin_amdgcn_exp2f(-ga)); \
    float B = __builtin_amdgcn_rcpf(1.f + __builtin_amdgcn_exp2f(-gb)); \
    float rA = __int_as_float(DPP(0x128, __float_as_int(A))); \
    float rB = __int_as_float(DPP(0x128, __float_as_int(B))); \
    float si = pm ? rA : A; \
    float sf = pm ? rB : B; \
    float s2 = pm ? A : rA; \
    float so = pm ? B : rB; \
    float tg = fmaf(2.f, s2, -1.f); \
    ccur = fmaf(sf, ccur, si * tg); \
    float tc = fmaf(2.f, __builtin_amdgcn_rcpf(1.f + __builtin_amdgcn_exp2f(ccur * -TWO_LOG2E)), -1.f); \
    hcur = so * tc;

#define BODY16_PF(SL) do { \
    XDOTS16(SL); \
    SL = *(const int4*)gnext; gnext += CHUNK; \
    DPP_GATHER(); \
    HDOTS16(); \
    ACT16(); \
    *yp = hcur; yp += CHUNK; \
} while (0)

#define BODY16_NT(SL) do { \
    XDOTS16(SL); \
    DPP_GATHER(); \
    HDOTS16(); \
    ACT16(); \
    *yp = hcur; yp += CHUNK; \
} while (0)

__global__ __launch_bounds__(64, 1) void k_lstm4(
        const _Float16* __restrict__ xh, const float* __restrict__ cost,
        const float* __restrict__ bcost, const float* __restrict__ h0,
        const float* __restrict__ c0, const float* __restrict__ Wih,
        const float* __restrict__ Whh, const float* __restrict__ bih,
        const float* __restrict__ bhh, float* __restrict__ ys,
        float* __restrict__ outhc)
{
    int lane = threadIdx.x;
    int u = lane & 7;
    int p = (lane >> 3) & 1;
    int bw = lane >> 4;
    int b = blockIdx.x * 4 + bw;
    int b8 = b * 8;
    bool pm = (p != 0);

    // own gates: qa = 2p, qb = 2p+1 (i,f | g,o); Whh in XOR-gather order
    const int xm[8] = {0, 1, 2, 3, 7, 6, 5, 4};
    half2_t wi_pk[2][4], wh_pk[2][4];
    float cbv[2];
    #pragma unroll
    for (int gi = 0; gi < 2; ++gi) {
        int q = 2 * p + gi;
        int r = q * 8 + u;
        float ks = (q == 2) ? TWO_LOG2E : LOG2E;
        #pragma unroll
        for (int pp = 0; pp < 4; ++pp) {
            half2_t wi = {(_Float16)(Wih[r * 10 + 2 * pp] * ks),
                          (_Float16)(Wih[r * 10 + 2 * pp + 1] * ks)};
            wi_pk[gi][pp] = wi;
            half2_t wh = {(_Float16)(Whh[r * 8 + (u ^ xm[2 * pp])] * ks),
                          (_Float16)(Whh[r * 8 + (u ^ xm[2 * pp + 1])] * ks)};
            wh_pk[gi][pp] = wh;
        }
        cbv[gi] = (bih[r] + bhh[r] + Wih[r * 10 + 8] * cost[b] + Wih[r * 10 + 9] * bcost[b]) * ks;
    }
    float hcur = h0[b8 + u], ccur = c0[b8 + u];

    const _Float16* gp = xh + b8;
    int4 S0 = *(const int4*)(gp + 0 * CHUNK);
    int4 S1 = *(const int4*)(gp + 1 * CHUNK);
    int4 S2 = *(const int4*)(gp + 2 * CHUNK);
    int4 S3 = *(const int4*)(gp + 3 * CHUNK);
    int4 S4 = *(const int4*)(gp + 4 * CHUNK);
    int4 S5 = *(const int4*)(gp + 5 * CHUNK);
    int4 S6 = *(const int4*)(gp + 6 * CHUNK);
    int4 S7 = *(const int4*)(gp + 7 * CHUNK);
    const _Float16* gnext = gp + 8 * CHUNK;
    float* yp = ys + b8 + u;

    for (int t = 0; t < 9992; t += 8) {
        BODY16_PF(S0);
        BODY16_PF(S1);
        BODY16_PF(S2);
        BODY16_PF(S3);
        BODY16_PF(S4);
        BODY16_PF(S5);
        BODY16_PF(S6);
        BODY16_PF(S7);
    }
    BODY16_NT(S0);
    BODY16_NT(S1);
    BODY16_NT(S2);
    BODY16_NT(S3);
    BODY16_NT(S4);
    BODY16_NT(S5);
    BODY16_NT(S6);
    BODY16_NT(S7);

    outhc[OUT_H + b8 + u] = hcur;
    outhc[OUT_C + b8 + u] = ccur;
}

// ---------------- kernel 4: softmax rows + attn @ V (denominator folded) ----------------
__global__ __launch_bounds__(256) void k_softmax_av(const float* __restrict__ ys,
        const float* __restrict__ V, float* __restrict__ heads)
{
    __shared__ float P[Gn * 101];
    __shared__ float Vs[Gn * 33];
    __shared__ float pm[256];
    __shared__ float rmaxs[Gn];
    __shared__ float rinvs[Gn];
    const float* ysrc = ys + (size_t)blockIdx.x * GG;
    for (int idx = threadIdx.x; idx < GG; idx += 256) {
        int i = idx / 100, j = idx - i * 100;
        P[i * 101 + j] = ysrc[idx];
    }
    const float* vsrc = V + (size_t)blockIdx.x * (Gn * KD);
    for (int idx = threadIdx.x; idx < Gn * KD; idx += 256) {
        int i = idx >> 5, d = idx & 31;
        Vs[i * 33 + d] = vsrc[idx];
    }
    __syncthreads();
    int t = threadIdx.x;
    if (t < 200) {
        const float* row = P + (t >> 1) * 101 + (t & 1) * 50;
        float m = -1e30f;
        #pragma unroll 5
        for (int j = 0; j < 50; ++j) m = fmaxf(m, row[j]);
        pm[t] = m;
    }
    __syncthreads();
    if (t < Gn) rmaxs[t] = fmaxf(pm[2 * t], pm[2 * t + 1]);
    __syncthreads();
    if (t < 200) {
        float* row = P + (t >> 1) * 101 + (t & 1) * 50;
        float m = rmaxs[t >> 1];
        float ss = 0.f;
        #pragma unroll 5
        for (int j = 0; j < 50; ++j) {
            float e = __builtin_amdgcn_exp2f((row[j] - m) * LOG2E);
            row[j] = e; ss += e;
        }
        pm[t] = ss;
    }
    __syncthreads();
    if (t < Gn) rinvs[t] = __builtin_amdgcn_rcpf(pm[2 * t] + pm[2 * t + 1]);
    __syncthreads();
    int d = t & 31, ii = t >> 5;
    float* hb = heads + (size_t)blockIdx.x * (Gn * KD);
    for (int i0 = 0; i0 < Gn; i0 += 8) {
        int i = i0 + ii;
        if (i < Gn) {
            float acc = 0.f;
            #pragma unroll 4
            for (int j = 0; j < Gn; ++j)
                acc = fmaf(P[i * 101 + j], Vs[j * 33 + d], acc);
            hb[i * KD + d] = acc * rinvs[i];
        }
    }
}

// ---------------- kernel 5: output projection ----------------
__global__ __launch_bounds__(256) void k_outproj(const float* __restrict__ heads,
        const float* __restrict__ Wo, float* __restrict__ out)
{
    int b = blockIdx.x / 13, p = blockIdx.x % 13;
    int e = threadIdx.x & 127, half = threadIdx.x >> 7;
    int r0 = p * 8 + half * 4;
    float acc0 = 0.f, acc1 = 0.f, acc2 = 0.f, acc3 = 0.f;
    for (int h = 0; h < NH; ++h) {
        const float* hs = heads + (size_t)h * (256 * Gn * KD) + (size_t)b * (Gn * KD);
        const float* wsrc = Wo + h * (KD * IND);
        #pragma unroll 8
        for (int d = 0; d < KD; ++d) {
            float w = wsrc[d * IND + e];
            if (r0 + 3 < Gn) {
                acc0 = fmaf(hs[(r0 + 0) * KD + d], w, acc0);
                acc1 = fmaf(hs[(r0 + 1) * KD + d], w, acc1);
                acc2 = fmaf(hs[(r0 + 2) * KD + d], w, acc2);
                acc3 = fmaf(hs[(r0 + 3) * KD + d], w, acc3);
            } else {
                if (r0 + 0 < Gn) acc0 = fmaf(hs[(r0 + 0) * KD + d], w, acc0);
                if (r0 + 1 < Gn) acc1 = fmaf(hs[(r0 + 1) * KD + d], w, acc1);
                if (r0 + 2 < Gn) acc2 = fmaf(hs[(r0 + 2) * KD + d], w, acc2);
                if (r0 + 3 < Gn) acc3 = fmaf(hs[(r0 + 3) * KD + d], w, acc3);
            }
        }
    }
    if (r0 + 0 < Gn) out[((size_t)b * Gn + r0 + 0) * IND + e] = acc0;
    if (r0 + 1 < Gn) out[((size_t)b * Gn + r0 + 1) * IND + e] = acc1;
    if (r0 + 2 < Gn) out[((size_t)b * Gn + r0 + 2) * IND + e] = acc2;
    if (r0 + 3 < Gn) out[((size_t)b * Gn + r0 + 3) * IND + e] = acc3;
}

extern "C" void kernel_launch(void* const* d_in, const int* in_sizes, int n_in,
                              void* d_out, int out_size, void* d_ws, size_t ws_size,
                              hipStream_t stream) {
    const float* X     = (const float*)d_in[0];
    const float* pos   = (const float*)d_in[1];
    const float* best  = (const float*)d_in[2];
    const float* cost  = (const float*)d_in[3];
    const float* bcost = (const float*)d_in[4];
    const float* h0    = (const float*)d_in[5];
    const float* c0    = (const float*)d_in[6];
    const float* Wq    = (const float*)d_in[7];
    const float* Wk    = (const float*)d_in[8];
    const float* Wv    = (const float*)d_in[9];
    const float* Wo    = (const float*)d_in[10];
    const float* Wih   = (const float*)d_in[11];
    const float* Whh   = (const float*)d_in[12];
    const float* bih   = (const float*)d_in[13];
    const float* bhh   = (const float*)d_in[14];
    float* out = (float*)d_out;
    char* ws = (char*)d_ws;

    if (ws_size < WS_MIN) {
        k_wsfail<<<1, 1, 0, stream>>>(out, (float)ws_size);
        return;
    }

    float* ysw      = (float*)(ws);
    float* Vw       = (float*)(ws + V_OFF);
    _Float16* xhw   = (_Float16*)(ws + XH_OFF);
    float* headsw   = (float*)(ws + HEADS_OFF);   // xh region, dead after LSTM

    k_qk_comp<<<1024, 256, 0, stream>>>(X, Wq, Wk, xhw);
    k_cast<<<2048, 256, 0, stream>>>(pos, best, xhw);
    k_vproj<<<2048, 256, 0, stream>>>(X, Wv, Vw);
    k_lstm4<<<64, 64, 0, stream>>>(xhw, cost, bcost, h0, c0,
                                   Wih, Whh, bih, bhh, ysw, out);
    k_softmax_av<<<2048, 256, 0, stream>>>(ysw, Vw, headsw);
    k_outproj<<<256 * 13, 256, 0, stream>>>(headsw, Wo, out);
}